// Round 1
// baseline (6727.486 us; speedup 1.0000x reference)
//
#include <hip/hip_runtime.h>
#include <cstdint>
#include <cmath>

typedef unsigned short u16;
typedef unsigned int u32;
typedef short bf16x8 __attribute__((ext_vector_type(8)));
typedef float f32x4 __attribute__((ext_vector_type(4)));

#define DEV static __device__ __forceinline__

DEV u16 f2bf(float f) {
  union { float f; u32 u; } v; v.f = f;
  return (u16)((v.u + 0x7FFFu + ((v.u >> 16) & 1u)) >> 16);
}

// ---------------------------------------------------------------------------
// Generic batched GEMM: C = epi(A_bf16 @ B + ...)
// MODE 0: B f32 [K][N],  out bf16              (Q,K projections)
// MODE 5: B f32 [K][N],  out bf16 TRANSPOSED   (V projection -> Vt[D][T])
// MODE 1: B bf16 [N][K] (transB), out f32 * scale   (Q @ K^T)
// MODE 2: B bf16 [N][K] (transB), out f32 +=        (P @ V, residual into H)
// MODE 3: B f32 [K][N],  out bf16 = gelu(acc + bias)    (MLP up)
// MODE 4: B f32 [K][N],  out f32 += acc + bias          (MLP down into H)
// ---------------------------------------------------------------------------
template<int MODE>
__global__ __launch_bounds__(256)
void gemm_k(const u16* __restrict__ A, const void* __restrict__ Bv,
            void* __restrict__ Cv, const float* __restrict__ bias,
            int M, int N, int K, long sA, long sB, long sC, float scale)
{
  constexpr bool TRB = (MODE == 1 || MODE == 2);

  __shared__ __align__(16) u16 As[128][40];       // [row][k], pad 40 to break bank stride
  __shared__ __align__(16) u16 Bs[4][128][8];     // [k/8][col][k%8] -> b128 frag reads

  const int bz = blockIdx.z;
  const int m0 = blockIdx.x * 128, n0 = blockIdx.y * 128;
  const int t = threadIdx.x;
  const int wave = t >> 6, lane = t & 63;
  const int wr = (wave >> 1) * 64, wc = (wave & 1) * 64;
  const int lg = lane >> 4, lr = lane & 15;

  const u16* Ab = A + (long)bz * sA;

  f32x4 acc[4][4];
  #pragma unroll
  for (int i = 0; i < 4; ++i)
    #pragma unroll
    for (int j = 0; j < 4; ++j)
      acc[i][j] = (f32x4){0.f, 0.f, 0.f, 0.f};

  for (int k0 = 0; k0 < K; k0 += 32) {
    // ---- stage A tile [128][32] bf16 ----
    {
      const int r = t >> 2, kq = (t & 3) * 8;
      #pragma unroll
      for (int p = 0; p < 2; ++p) {
        const int rr = r + p * 64;
        *reinterpret_cast<uint4*>(&As[rr][kq]) =
            *reinterpret_cast<const uint4*>(Ab + (long)(m0 + rr) * K + k0 + kq);
      }
    }
    // ---- stage B tile ----
    if constexpr (TRB) {
      const u16* Bb = (const u16*)Bv + (long)bz * sB;
      const int n = t >> 2, kq = (t & 3) * 8;
      #pragma unroll
      for (int p = 0; p < 2; ++p) {
        const int nn = n + p * 64;
        *reinterpret_cast<uint4*>(&Bs[kq >> 3][nn][0]) =
            *reinterpret_cast<const uint4*>(Bb + (long)(n0 + nn) * K + k0 + kq);
      }
    } else {
      const float* Bb = (const float*)Bv + (long)bz * sB;
      const int n = t & 127, kh = t >> 7;          // 2 k-halves of 16
      const float* src = Bb + (long)(k0 + kh * 16) * N + n0 + n;
      u32 pk[8];
      #pragma unroll
      for (int j = 0; j < 8; ++j) {
        const u16 lo = f2bf(src[(long)(2 * j) * N]);
        const u16 hi = f2bf(src[(long)(2 * j + 1) * N]);
        pk[j] = (u32)lo | ((u32)hi << 16);
      }
      *reinterpret_cast<uint4*>(&Bs[kh * 2][n][0])     = make_uint4(pk[0], pk[1], pk[2], pk[3]);
      *reinterpret_cast<uint4*>(&Bs[kh * 2 + 1][n][0]) = make_uint4(pk[4], pk[5], pk[6], pk[7]);
    }
    __syncthreads();

    bf16x8 af[4], bfr[4];
    #pragma unroll
    for (int i = 0; i < 4; ++i)
      af[i] = *reinterpret_cast<const bf16x8*>(&As[wr + i * 16 + lr][lg * 8]);
    #pragma unroll
    for (int i = 0; i < 4; ++i)
      bfr[i] = *reinterpret_cast<const bf16x8*>(&Bs[lg][wc + i * 16 + lr][0]);

    #pragma unroll
    for (int mi = 0; mi < 4; ++mi)
      #pragma unroll
      for (int ni = 0; ni < 4; ++ni)
        acc[mi][ni] = __builtin_amdgcn_mfma_f32_16x16x32_bf16(af[mi], bfr[ni], acc[mi][ni], 0, 0, 0);

    __syncthreads();
  }

  // ---- epilogue ----
  #pragma unroll
  for (int mi = 0; mi < 4; ++mi) {
    #pragma unroll
    for (int ni = 0; ni < 4; ++ni) {
      #pragma unroll
      for (int r = 0; r < 4; ++r) {
        const int grow = m0 + wr + mi * 16 + lg * 4 + r;
        const int gcol = n0 + wc + ni * 16 + lr;
        const float v = acc[mi][ni][r];
        if constexpr (MODE == 0) {
          u16* Cp = (u16*)Cv + (long)bz * sC;
          Cp[(long)grow * N + gcol] = f2bf(v);
        } else if constexpr (MODE == 5) {
          u16* Cp = (u16*)Cv + (long)bz * sC;
          Cp[(long)gcol * M + grow] = f2bf(v);
        } else if constexpr (MODE == 1) {
          float* Cp = (float*)Cv + (long)bz * sC;
          Cp[(long)grow * N + gcol] = v * scale;
        } else if constexpr (MODE == 2) {
          float* Cp = (float*)Cv + (long)bz * sC;
          const long idx = (long)grow * N + gcol;
          Cp[idx] += v;
        } else if constexpr (MODE == 3) {
          u16* Cp = (u16*)Cv + (long)bz * sC;
          const float x = v + bias[gcol];
          const float ge = 0.5f * x * (1.0f + erff(x * 0.70710678118f));
          Cp[(long)grow * N + gcol] = f2bf(ge);
        } else if constexpr (MODE == 4) {
          float* Cp = (float*)Cv + (long)bz * sC;
          const long idx = (long)grow * N + gcol;
          Cp[idx] = Cp[idx] + v + bias[gcol];
        }
      }
    }
  }
}

// ---------------------------------------------------------------------------
// Embedding: H[b][t][:] = (t<512 ? quadratic-leave : t_emb[xt]) + pos_emb[t]
// ---------------------------------------------------------------------------
__global__ __launch_bounds__(256)
void embed_k(const int* __restrict__ xt, const int* __restrict__ zi,
             const float* __restrict__ pos, const float* __restrict__ temb,
             float* __restrict__ H)
{
  const int bt = blockIdx.x;
  const int b = bt >> 10, tk = bt & 1023;
  const int d = threadIdx.x * 4;
  const float4 p = reinterpret_cast<const float4*>(pos + (long)tk * 1024)[threadIdx.x];
  float4 v;
  if (tk < 512) {
    const float z = (float)zi[b * 512 + tk];
    float c0 = (float)(d + 0) - z, c1 = (float)(d + 1) - z;
    float c2 = (float)(d + 2) - z, c3 = (float)(d + 3) - z;
    v.x = (d + 0 < 10) ? -0.5f * c0 * c0 : 0.f;
    v.y = (d + 1 < 10) ? -0.5f * c1 * c1 : 0.f;
    v.z = (d + 2 < 10) ? -0.5f * c2 * c2 : 0.f;
    v.w = (d + 3 < 10) ? -0.5f * c3 * c3 : 0.f;
  } else {
    const float* te = temb + (long)xt[b * 512 + (tk - 512)] * 1024;
    v = reinterpret_cast<const float4*>(te)[threadIdx.x];
  }
  float4 o; o.x = v.x + p.x; o.y = v.y + p.y; o.z = v.z + p.z; o.w = v.w + p.w;
  reinterpret_cast<float4*>(H + (long)bt * 1024)[threadIdx.x] = o;
}

// ---------------------------------------------------------------------------
// LayerNorm over D=1024, f32 in -> bf16 out
// ---------------------------------------------------------------------------
__global__ __launch_bounds__(256)
void ln_k(const float* __restrict__ X, const float* __restrict__ g,
          const float* __restrict__ bta, u16* __restrict__ Y)
{
  __shared__ float sm[8];
  const long row = blockIdx.x;
  const float4 x = reinterpret_cast<const float4*>(X + row * 1024)[threadIdx.x];
  float s1 = x.x + x.y + x.z + x.w;
  float s2 = x.x * x.x + x.y * x.y + x.z * x.z + x.w * x.w;
  #pragma unroll
  for (int o = 32; o > 0; o >>= 1) { s1 += __shfl_down(s1, o); s2 += __shfl_down(s2, o); }
  const int w = threadIdx.x >> 6, ln = threadIdx.x & 63;
  if (ln == 0) { sm[w] = s1; sm[4 + w] = s2; }
  __syncthreads();
  s1 = sm[0] + sm[1] + sm[2] + sm[3];
  s2 = sm[4] + sm[5] + sm[6] + sm[7];
  const float mu = s1 * (1.f / 1024.f);
  const float var = s2 * (1.f / 1024.f) - mu * mu;
  const float inv = rsqrtf(var + 1e-5f);
  const float4 gg = reinterpret_cast<const float4*>(g)[threadIdx.x];
  const float4 bb = reinterpret_cast<const float4*>(bta)[threadIdx.x];
  u32 o0 = (u32)f2bf((x.x - mu) * inv * gg.x + bb.x) | ((u32)f2bf((x.y - mu) * inv * gg.y + bb.y) << 16);
  u32 o1 = (u32)f2bf((x.z - mu) * inv * gg.z + bb.z) | ((u32)f2bf((x.w - mu) * inv * gg.w + bb.w) << 16);
  reinterpret_cast<uint2*>(Y + row * 1024)[threadIdx.x] = make_uint2(o0, o1);
}

// ---------------------------------------------------------------------------
// Row softmax over 1024 cols, f32 in -> bf16 out
// ---------------------------------------------------------------------------
__global__ __launch_bounds__(256)
void sm_k(const float* __restrict__ S, u16* __restrict__ P)
{
  __shared__ float sm[8];
  const long row = blockIdx.x;
  const float4 x = reinterpret_cast<const float4*>(S + row * 1024)[threadIdx.x];
  float m = fmaxf(fmaxf(x.x, x.y), fmaxf(x.z, x.w));
  #pragma unroll
  for (int o = 32; o > 0; o >>= 1) m = fmaxf(m, __shfl_down(m, o));
  const int w = threadIdx.x >> 6, ln = threadIdx.x & 63;
  if (ln == 0) sm[w] = m;
  __syncthreads();
  m = fmaxf(fmaxf(sm[0], sm[1]), fmaxf(sm[2], sm[3]));
  const float e0 = __expf(x.x - m), e1 = __expf(x.y - m);
  const float e2 = __expf(x.z - m), e3 = __expf(x.w - m);
  float s = e0 + e1 + e2 + e3;
  #pragma unroll
  for (int o = 32; o > 0; o >>= 1) s += __shfl_down(s, o);
  if (ln == 0) sm[4 + w] = s;
  __syncthreads();
  const float tot = sm[4] + sm[5] + sm[6] + sm[7];
  const float r = 1.0f / tot;
  u32 o0 = (u32)f2bf(e0 * r) | ((u32)f2bf(e1 * r) << 16);
  u32 o1 = (u32)f2bf(e2 * r) | ((u32)f2bf(e3 * r) << 16);
  reinterpret_cast<uint2*>(P + row * 1024)[threadIdx.x] = make_uint2(o0, o1);
}

// ---------------------------------------------------------------------------
// Readout: out[b*512+i] = dot(H[b][i][:], ro_w) + ro_b
// ---------------------------------------------------------------------------
__global__ __launch_bounds__(256)
void ro_k(const float* __restrict__ H, const float* __restrict__ w,
          const float* __restrict__ b, float* __restrict__ out)
{
  __shared__ float sm[4];
  const int row = blockIdx.x;
  const int bb = row >> 9, i = row & 511;
  const float* h = H + ((long)bb * 1024 + i) * 1024;
  const float4 x = reinterpret_cast<const float4*>(h)[threadIdx.x];
  const float4 ww = reinterpret_cast<const float4*>(w)[threadIdx.x];
  float s = x.x * ww.x + x.y * ww.y + x.z * ww.z + x.w * ww.w;
  #pragma unroll
  for (int o = 32; o > 0; o >>= 1) s += __shfl_down(s, o);
  const int wv = threadIdx.x >> 6, ln = threadIdx.x & 63;
  if (ln == 0) sm[wv] = s;
  __syncthreads();
  if (threadIdx.x == 0) out[row] = sm[0] + sm[1] + sm[2] + sm[3] + b[0];
}

// ---------------------------------------------------------------------------
extern "C" void kernel_launch(void* const* d_in, const int* in_sizes, int n_in,
                              void* d_out, int out_size, void* d_ws, size_t ws_size,
                              hipStream_t stream)
{
  const int* xt = (const int*)d_in[0];
  const int* zi = (const int*)d_in[1];
  const float* pos  = (const float*)d_in[2];
  const float* temb = (const float*)d_in[3];
  const float* Wq = (const float*)d_in[4];
  const float* Wk = (const float*)d_in[5];
  const float* Wv = (const float*)d_in[6];
  const float* ln1g = (const float*)d_in[7];
  const float* ln1b = (const float*)d_in[8];
  const float* ln2g = (const float*)d_in[9];
  const float* ln2b = (const float*)d_in[10];
  const float* w1 = (const float*)d_in[11];
  const float* b1 = (const float*)d_in[12];
  const float* w2 = (const float*)d_in[13];
  const float* b2 = (const float*)d_in[14];
  const float* row_w = (const float*)d_in[15];
  const float* row_b = (const float*)d_in[16];

  char* ws = (char*)d_ws;
  const long MB = 1024 * 1024;
  float* H   = (float*)(ws + 0);          // 32 MB  [8][1024][1024] f32
  u16*   H1  = (u16*)(ws + 32 * MB);      // 16 MB  [8192][1024] bf16
  u16*   Qb  = (u16*)(ws + 48 * MB);      // 16 MB
  u16*   Kb  = (u16*)(ws + 64 * MB);      // 16 MB
  u16*   Vt  = (u16*)(ws + 80 * MB);      // 16 MB  [8][1024(d)][1024(t)]
  float* S   = (float*)(ws + 96 * MB);    // 32 MB  [8][1024][1024] f32
  u16*   P   = (u16*)(ws + 128 * MB);     // 16 MB
  u16*   G   = (u16*)(ws + 144 * MB);     // 64 MB  [8192][4096] bf16

  const long s1M = 1024L * 1024L;

  embed_k<<<8192, 256, 0, stream>>>(xt, zi, pos, temb, H);

  for (int l = 0; l < 12; ++l) {
    const float* wq = Wq + (long)l * s1M;
    const float* wk = Wk + (long)l * s1M;
    const float* wv = Wv + (long)l * s1M;
    const float* mw1 = w1 + (long)l * 1024L * 4096L;
    const float* mb1 = b1 + (long)l * 4096L;
    const float* mw2 = w2 + (long)l * 4096L * 1024L;
    const float* mb2 = b2 + (long)l * 1024L;

    ln_k<<<8192, 256, 0, stream>>>(H, ln1g + l * 1024, ln1b + l * 1024, H1);

    gemm_k<0><<<dim3(8, 8, 8), 256, 0, stream>>>(H1, wq, Qb, nullptr, 1024, 1024, 1024, s1M, 0, s1M, 1.f);
    gemm_k<0><<<dim3(8, 8, 8), 256, 0, stream>>>(H1, wk, Kb, nullptr, 1024, 1024, 1024, s1M, 0, s1M, 1.f);
    gemm_k<5><<<dim3(8, 8, 8), 256, 0, stream>>>(H1, wv, Vt, nullptr, 1024, 1024, 1024, s1M, 0, s1M, 1.f);

    gemm_k<1><<<dim3(8, 8, 8), 256, 0, stream>>>(Qb, Kb, S, nullptr, 1024, 1024, 1024, s1M, s1M, s1M, 1.f / 32.f);

    sm_k<<<8192, 256, 0, stream>>>(S, P);

    gemm_k<2><<<dim3(8, 8, 8), 256, 0, stream>>>(P, Vt, H, nullptr, 1024, 1024, 1024, s1M, s1M, s1M, 1.f);

    ln_k<<<8192, 256, 0, stream>>>(H, ln2g + l * 1024, ln2b + l * 1024, H1);

    gemm_k<3><<<dim3(64, 32, 1), 256, 0, stream>>>(H1, mw1, G, mb1, 8192, 4096, 1024, 0, 0, 0, 1.f);
    gemm_k<4><<<dim3(64, 8, 1), 256, 0, stream>>>(G, mw2, H, mb2, 8192, 1024, 4096, 0, 0, 0, 1.f);
  }

  ro_k<<<4096, 256, 0, stream>>>(H, row_w, row_b, (float*)d_out);
}

// Round 2
// 5237.090 us; speedup vs baseline: 1.2846x; 1.2846x over previous
//
#include <hip/hip_runtime.h>
#include <cstdint>
#include <cmath>

typedef unsigned short u16;
typedef unsigned int u32;
typedef short bf16x8 __attribute__((ext_vector_type(8)));
typedef float f32x4 __attribute__((ext_vector_type(4)));

#define DEV static __device__ __forceinline__

DEV u16 f2bf(float f) {
  union { float f; u32 u; } v; v.f = f;
  return (u16)((v.u + 0x7FFFu + ((v.u >> 16) & 1u)) >> 16);
}

DEV void gload16(const u16* g, u16* l) {
  __builtin_amdgcn_global_load_lds(
      (const __attribute__((address_space(1))) void*)g,
      (__attribute__((address_space(3))) void*)l, 16, 0, 0);
}

// ---------------------------------------------------------------------------
// bf16 GEMM, m97 structure: A [M][K] bf16, Bt [N][K] bf16 (i.e. B^T), 128x128
// tile, BK=32, 4 waves, global_load_lds width-16 staging, linear LDS.
// MODE 0: out bf16                       (Q/K proj, Vt)
// MODE 1: out f32 * scale                (Q @ K^T)
// MODE 2: out f32 +=                     (P @ V residual into H)
// MODE 3: out bf16 = gelu(acc + bias)    (MLP up)
// MODE 4: out f32 += acc + bias          (MLP down into H)
// ---------------------------------------------------------------------------
template<int MODE>
__global__ __launch_bounds__(256)
void gemm2(const u16* __restrict__ A, const u16* __restrict__ Bt,
           void* __restrict__ Cv, const float* __restrict__ bias,
           int M, int N, int K, long sA, long sB, long sC, float scale)
{
  __shared__ __align__(16) u16 As[128 * 32];
  __shared__ __align__(16) u16 Bs[128 * 32];

  const int bz = blockIdx.z;
  const long m0 = (long)blockIdx.x * 128, n0 = (long)blockIdx.y * 128;
  const int t = threadIdx.x;
  const int wave = t >> 6, lane = t & 63;
  const int wr = (wave >> 1) * 64, wc = (wave & 1) * 64;
  const int lg = lane >> 4, lr = lane & 15;

  // staging: chunk c = wave*2+j covers rows [c*16, c*16+16); HW writes
  // wave-uniform LDS base + lane*16B. lane i -> row c*16 + (i>>2), k (i&3)*8.
  const int rS = wave * 32 + (lane >> 2);
  const int kq = (lane & 3) * 8;
  const u16* aS = A  + (long)bz * sA + (m0 + rS) * (long)K + kq;
  const u16* bS = Bt + (long)bz * sB + (n0 + rS) * (long)K + kq;
  u16* aD = As + wave * 1024;   // u16 units; chunk j=1 at +512
  u16* bD = Bs + wave * 1024;
  const long rowK16 = 16L * K;

  f32x4 acc[4][4];
  #pragma unroll
  for (int i = 0; i < 4; ++i)
    #pragma unroll
    for (int j = 0; j < 4; ++j)
      acc[i][j] = (f32x4){0.f, 0.f, 0.f, 0.f};

  for (int k0 = 0; k0 < K; k0 += 32) {
    gload16(aS,          aD);
    gload16(aS + rowK16, aD + 512);
    gload16(bS,          bD);
    gload16(bS + rowK16, bD + 512);
    aS += 32; bS += 32;
    __syncthreads();

    bf16x8 af[4], bg[4];
    #pragma unroll
    for (int i = 0; i < 4; ++i)
      af[i] = *reinterpret_cast<const bf16x8*>(As + (wr + i * 16 + lr) * 32 + lg * 8);
    #pragma unroll
    for (int i = 0; i < 4; ++i)
      bg[i] = *reinterpret_cast<const bf16x8*>(Bs + (wc + i * 16 + lr) * 32 + lg * 8);

    #pragma unroll
    for (int mi = 0; mi < 4; ++mi)
      #pragma unroll
      for (int ni = 0; ni < 4; ++ni)
        acc[mi][ni] = __builtin_amdgcn_mfma_f32_16x16x32_bf16(af[mi], bg[ni], acc[mi][ni], 0, 0, 0);

    __syncthreads();
  }

  #pragma unroll
  for (int mi = 0; mi < 4; ++mi) {
    #pragma unroll
    for (int ni = 0; ni < 4; ++ni) {
      #pragma unroll
      for (int r = 0; r < 4; ++r) {
        const long grow = m0 + wr + mi * 16 + lg * 4 + r;
        const long gcol = n0 + wc + ni * 16 + lr;
        const float v = acc[mi][ni][r];
        if constexpr (MODE == 0) {
          u16* Cp = (u16*)Cv + (long)bz * sC;
          Cp[grow * N + gcol] = f2bf(v);
        } else if constexpr (MODE == 1) {
          float* Cp = (float*)Cv + (long)bz * sC;
          Cp[grow * N + gcol] = v * scale;
        } else if constexpr (MODE == 2) {
          float* Cp = (float*)Cv + (long)bz * sC;
          Cp[grow * N + gcol] += v;
        } else if constexpr (MODE == 3) {
          u16* Cp = (u16*)Cv + (long)bz * sC;
          const float x = v + bias[gcol];
          const float ge = 0.5f * x * (1.0f + erff(x * 0.70710678118f));
          Cp[grow * N + gcol] = f2bf(ge);
        } else if constexpr (MODE == 4) {
          float* Cp = (float*)Cv + (long)bz * sC;
          const long idx = grow * N + gcol;
          Cp[idx] = Cp[idx] + v + bias[gcol];
        }
      }
    }
  }
}

// ---------------------------------------------------------------------------
// Per-layer weight transpose+convert: f32 [K][N] -> bf16 [N][K].
// One launch covers wq, wk, wv (1024x1024), w1 (1024x4096), w2 (4096x1024).
// Tiles 64x64, block 256. Outputs: WqT+0, WkT+1M, WvT+2M, W1T+3M, W2T+7M (u16)
// ---------------------------------------------------------------------------
__global__ __launch_bounds__(256)
void trans_k(const float* __restrict__ wq, const float* __restrict__ wk,
             const float* __restrict__ wv, const float* __restrict__ w1,
             const float* __restrict__ w2, u16* __restrict__ ob)
{
  __shared__ u16 T[64][68];
  const int b = blockIdx.x;
  const float* in; u16* out; int K, N, tk, tn;
  if (b < 768) {
    const int m = b >> 8, tt = b & 255;
    in = (m == 0) ? wq : (m == 1) ? wk : wv;
    out = ob + (long)m * 1048576L;
    K = 1024; N = 1024; tk = tt >> 4; tn = tt & 15;
  } else if (b < 1792) {
    const int tt = b - 768;
    in = w1; out = ob + 3L * 1048576L; K = 1024; N = 4096;
    tk = tt >> 6; tn = tt & 63;
  } else {
    const int tt = b - 1792;
    in = w2; out = ob + 7L * 1048576L; K = 4096; N = 1024;
    tk = tt >> 4; tn = tt & 15;
  }
  const int k0 = tk * 64, n0 = tn * 64;
  const int t = threadIdx.x;
  {
    const int r = t >> 2, cq = (t & 3) * 16;
    const float* src = in + (long)(k0 + r) * N + n0 + cq;
    #pragma unroll
    for (int q = 0; q < 4; ++q) {
      const float4 v = *reinterpret_cast<const float4*>(src + q * 4);
      T[r][cq + q * 4 + 0] = f2bf(v.x);
      T[r][cq + q * 4 + 1] = f2bf(v.y);
      T[r][cq + q * 4 + 2] = f2bf(v.z);
      T[r][cq + q * 4 + 3] = f2bf(v.w);
    }
  }
  __syncthreads();
  {
    const int n = t >> 2, kq2 = (t & 3) * 16;
    u16 tmp[16];
    #pragma unroll
    for (int j = 0; j < 16; ++j) tmp[j] = T[kq2 + j][n];
    uint4* dst = reinterpret_cast<uint4*>(out + (long)(n0 + n) * K + k0 + kq2);
    dst[0] = *reinterpret_cast<const uint4*>(&tmp[0]);
    dst[1] = *reinterpret_cast<const uint4*>(&tmp[8]);
  }
}

// ---------------------------------------------------------------------------
__global__ __launch_bounds__(256)
void embed_k(const int* __restrict__ xt, const int* __restrict__ zi,
             const float* __restrict__ pos, const float* __restrict__ temb,
             float* __restrict__ H)
{
  const int bt = blockIdx.x;
  const int b = bt >> 10, tk = bt & 1023;
  const int d = threadIdx.x * 4;
  const float4 p = reinterpret_cast<const float4*>(pos + (long)tk * 1024)[threadIdx.x];
  float4 v;
  if (tk < 512) {
    const float z = (float)zi[b * 512 + tk];
    const float c0 = (float)(d + 0) - z, c1 = (float)(d + 1) - z;
    const float c2 = (float)(d + 2) - z, c3 = (float)(d + 3) - z;
    v.x = (d + 0 < 10) ? -0.5f * c0 * c0 : 0.f;
    v.y = (d + 1 < 10) ? -0.5f * c1 * c1 : 0.f;
    v.z = (d + 2 < 10) ? -0.5f * c2 * c2 : 0.f;
    v.w = (d + 3 < 10) ? -0.5f * c3 * c3 : 0.f;
  } else {
    const float* te = temb + (long)xt[b * 512 + (tk - 512)] * 1024;
    v = reinterpret_cast<const float4*>(te)[threadIdx.x];
  }
  float4 o; o.x = v.x + p.x; o.y = v.y + p.y; o.z = v.z + p.z; o.w = v.w + p.w;
  reinterpret_cast<float4*>(H + (long)bt * 1024)[threadIdx.x] = o;
}

__global__ __launch_bounds__(256)
void ln_k(const float* __restrict__ X, const float* __restrict__ g,
          const float* __restrict__ bta, u16* __restrict__ Y)
{
  __shared__ float sm[8];
  const long row = blockIdx.x;
  const float4 x = reinterpret_cast<const float4*>(X + row * 1024)[threadIdx.x];
  float s1 = x.x + x.y + x.z + x.w;
  float s2 = x.x * x.x + x.y * x.y + x.z * x.z + x.w * x.w;
  #pragma unroll
  for (int o = 32; o > 0; o >>= 1) { s1 += __shfl_down(s1, o); s2 += __shfl_down(s2, o); }
  const int w = threadIdx.x >> 6, ln = threadIdx.x & 63;
  if (ln == 0) { sm[w] = s1; sm[4 + w] = s2; }
  __syncthreads();
  s1 = sm[0] + sm[1] + sm[2] + sm[3];
  s2 = sm[4] + sm[5] + sm[6] + sm[7];
  const float mu = s1 * (1.f / 1024.f);
  const float var = s2 * (1.f / 1024.f) - mu * mu;
  const float inv = rsqrtf(var + 1e-5f);
  const float4 gg = reinterpret_cast<const float4*>(g)[threadIdx.x];
  const float4 bb = reinterpret_cast<const float4*>(bta)[threadIdx.x];
  const u32 o0 = (u32)f2bf((x.x - mu) * inv * gg.x + bb.x) | ((u32)f2bf((x.y - mu) * inv * gg.y + bb.y) << 16);
  const u32 o1 = (u32)f2bf((x.z - mu) * inv * gg.z + bb.z) | ((u32)f2bf((x.w - mu) * inv * gg.w + bb.w) << 16);
  reinterpret_cast<uint2*>(Y + row * 1024)[threadIdx.x] = make_uint2(o0, o1);
}

__global__ __launch_bounds__(256)
void sm_k(const float* __restrict__ S, u16* __restrict__ P)
{
  __shared__ float sm[8];
  const long row = blockIdx.x;
  const float4 x = reinterpret_cast<const float4*>(S + row * 1024)[threadIdx.x];
  float m = fmaxf(fmaxf(x.x, x.y), fmaxf(x.z, x.w));
  #pragma unroll
  for (int o = 32; o > 0; o >>= 1) m = fmaxf(m, __shfl_down(m, o));
  const int w = threadIdx.x >> 6, ln = threadIdx.x & 63;
  if (ln == 0) sm[w] = m;
  __syncthreads();
  m = fmaxf(fmaxf(sm[0], sm[1]), fmaxf(sm[2], sm[3]));
  const float e0 = __expf(x.x - m), e1 = __expf(x.y - m);
  const float e2 = __expf(x.z - m), e3 = __expf(x.w - m);
  float s = e0 + e1 + e2 + e3;
  #pragma unroll
  for (int o = 32; o > 0; o >>= 1) s += __shfl_down(s, o);
  if (ln == 0) sm[4 + w] = s;
  __syncthreads();
  const float tot = sm[4] + sm[5] + sm[6] + sm[7];
  const float r = 1.0f / tot;
  const u32 o0 = (u32)f2bf(e0 * r) | ((u32)f2bf(e1 * r) << 16);
  const u32 o1 = (u32)f2bf(e2 * r) | ((u32)f2bf(e3 * r) << 16);
  reinterpret_cast<uint2*>(P + row * 1024)[threadIdx.x] = make_uint2(o0, o1);
}

__global__ __launch_bounds__(256)
void ro_k(const float* __restrict__ H, const float* __restrict__ w,
          const float* __restrict__ b, float* __restrict__ out)
{
  __shared__ float sm[4];
  const int row = blockIdx.x;
  const int bb = row >> 9, i = row & 511;
  const float* h = H + ((long)bb * 1024 + i) * 1024;
  const float4 x = reinterpret_cast<const float4*>(h)[threadIdx.x];
  const float4 ww = reinterpret_cast<const float4*>(w)[threadIdx.x];
  float s = x.x * ww.x + x.y * ww.y + x.z * ww.z + x.w * ww.w;
  #pragma unroll
  for (int o = 32; o > 0; o >>= 1) s += __shfl_down(s, o);
  const int wv = threadIdx.x >> 6, ln = threadIdx.x & 63;
  if (ln == 0) sm[wv] = s;
  __syncthreads();
  if (threadIdx.x == 0) out[row] = sm[0] + sm[1] + sm[2] + sm[3] + b[0];
}

// ---------------------------------------------------------------------------
extern "C" void kernel_launch(void* const* d_in, const int* in_sizes, int n_in,
                              void* d_out, int out_size, void* d_ws, size_t ws_size,
                              hipStream_t stream)
{
  const int* xt = (const int*)d_in[0];
  const int* zi = (const int*)d_in[1];
  const float* pos  = (const float*)d_in[2];
  const float* temb = (const float*)d_in[3];
  const float* Wq = (const float*)d_in[4];
  const float* Wk = (const float*)d_in[5];
  const float* Wv = (const float*)d_in[6];
  const float* ln1g = (const float*)d_in[7];
  const float* ln1b = (const float*)d_in[8];
  const float* ln2g = (const float*)d_in[9];
  const float* ln2b = (const float*)d_in[10];
  const float* w1 = (const float*)d_in[11];
  const float* b1 = (const float*)d_in[12];
  const float* w2 = (const float*)d_in[13];
  const float* b2 = (const float*)d_in[14];
  const float* row_w = (const float*)d_in[15];
  const float* row_b = (const float*)d_in[16];

  char* ws = (char*)d_ws;
  const long MB = 1024 * 1024;
  float* H   = (float*)(ws + 0);          // 32 MB  [8][1024][1024] f32
  u16*   H1  = (u16*)(ws + 32 * MB);      // 16 MB  [8192][1024] bf16
  u16*   Qb  = (u16*)(ws + 48 * MB);      // 16 MB
  u16*   Kb  = (u16*)(ws + 64 * MB);      // 16 MB
  u16*   Vt  = (u16*)(ws + 80 * MB);      // 16 MB  [8][1024(d)][1024(t)]
  float* S   = (float*)(ws + 96 * MB);    // 32 MB  f32
  u16*   P   = (u16*)(ws + 128 * MB);     // 16 MB
  u16*   G   = (u16*)(ws + 80 * MB);      // 64 MB, aliases Vt/S/P (dead in MLP)
  u16*   WT  = (u16*)(ws + 144 * MB);     // 22 MB  per-layer bf16 weights (B^T)

  u16* WqT = WT;
  u16* WkT = WT + 1048576L;
  u16* WvT = WT + 2 * 1048576L;
  u16* W1T = WT + 3 * 1048576L;           // [4096][1024]
  u16* W2T = WT + 7 * 1048576L;           // [1024][4096]

  const long s1M = 1024L * 1024L;

  embed_k<<<8192, 256, 0, stream>>>(xt, zi, pos, temb, H);

  for (int l = 0; l < 12; ++l) {
    const float* wq = Wq + (long)l * s1M;
    const float* wk = Wk + (long)l * s1M;
    const float* wv = Wv + (long)l * s1M;
    const float* mw1 = w1 + (long)l * 1024L * 4096L;
    const float* mb1 = b1 + (long)l * 4096L;
    const float* mw2 = w2 + (long)l * 4096L * 1024L;
    const float* mb2 = b2 + (long)l * 1024L;

    trans_k<<<2816, 256, 0, stream>>>(wq, wk, wv, mw1, mw2, WT);

    ln_k<<<8192, 256, 0, stream>>>(H, ln1g + l * 1024, ln1b + l * 1024, H1);

    // Q = H1 @ wq, K = H1 @ wk  (flat M=8192, shared weight)
    gemm2<0><<<dim3(64, 8, 1), 256, 0, stream>>>(H1, WqT, Qb, nullptr, 8192, 1024, 1024, 0, 0, 0, 1.f);
    gemm2<0><<<dim3(64, 8, 1), 256, 0, stream>>>(H1, WkT, Kb, nullptr, 8192, 1024, 1024, 0, 0, 0, 1.f);
    // Vt[b][d][t] = sum_k wv[k][d] H1[b][t][k]  (A=WvT shared, Bt=H1 batched)
    gemm2<0><<<dim3(8, 8, 8), 256, 0, stream>>>(WvT, H1, Vt, nullptr, 1024, 1024, 1024, 0, s1M, s1M, 1.f);

    // S = Q @ K^T / sqrt(D)
    gemm2<1><<<dim3(8, 8, 8), 256, 0, stream>>>(Qb, Kb, S, nullptr, 1024, 1024, 1024, s1M, s1M, s1M, 1.f / 32.f);

    sm_k<<<8192, 256, 0, stream>>>(S, P);

    // H += P @ V   (Bt = Vt[d][t])
    gemm2<2><<<dim3(8, 8, 8), 256, 0, stream>>>(P, Vt, (void*)H, nullptr, 1024, 1024, 1024, s1M, s1M, s1M, 1.f);

    ln_k<<<8192, 256, 0, stream>>>(H, ln2g + l * 1024, ln2b + l * 1024, H1);

    // G = gelu(H1 @ w1 + b1)
    gemm2<3><<<dim3(64, 32, 1), 256, 0, stream>>>(H1, W1T, G, mb1, 8192, 4096, 1024, 0, 0, 0, 1.f);
    // H += G @ w2 + b2
    gemm2<4><<<dim3(64, 8, 1), 256, 0, stream>>>(G, W2T, (void*)H, mb2, 8192, 1024, 4096, 0, 0, 0, 1.f);
  }

  ro_k<<<4096, 256, 0, stream>>>(H, row_w, row_b, (float*)d_out);
}

// Round 3
// 4934.603 us; speedup vs baseline: 1.3633x; 1.0613x over previous
//
#include <hip/hip_runtime.h>
#include <cstdint>
#include <cmath>

typedef unsigned short u16;
typedef unsigned int u32;
typedef short bf16x8 __attribute__((ext_vector_type(8)));
typedef float f32x4 __attribute__((ext_vector_type(4)));

#define DEV static __device__ __forceinline__

DEV u16 f2bf(float f) {
  union { float f; u32 u; } v; v.f = f;
  return (u16)((v.u + 0x7FFFu + ((v.u >> 16) & 1u)) >> 16);
}

DEV void bar() {
  asm volatile("" ::: "memory");
  __builtin_amdgcn_s_barrier();
  asm volatile("" ::: "memory");
}

// ---------------------------------------------------------------------------
// 256xBN 8-phase bf16 GEMM (T2 swizzle + T3/T4 counted-vmcnt + T5 setprio).
// A [M][K] bf16, Bt [N][K] bf16. BK=64, 8 waves (512 thr), 2-deep LDS dbuf.
// BN=256: U=4 stage units/tile {A0,B0,B1,A1}, vmcnt(6); LDS 128 KiB.
// BN=128: U=3 units {A0,B,A1}, vmcnt(4); LDS 96 KiB.
// Per tile: 4 phases, each {ds_read subtile | issue 1 unit prefetch | bar |
// lgkmcnt(0) | setprio(1) 16(or 8) MFMA setprio(0) | bar}; one counted vmcnt
// per tile at the boundary. Ledger: issue lead 2U-1 units => every region's
// overwriting prefetch issues >=1 barrier after its last ds_read (race-free).
// LDS swizzle: byte ^= (row&7)<<4 on reads; staging pre-swizzles the GLOBAL
// source so global_load_lds' linear LDS write lands swizzled (rule #21).
// MODE 0: out bf16 | 1: f32*scale | 2: f32 += | 3: bf16 gelu(acc+bias) |
// MODE 4: f32 += acc + bias
// ---------------------------------------------------------------------------
template<int MODE, int BN>
__global__ __launch_bounds__(512, 2)
void gemm8(const u16* __restrict__ A, const u16* __restrict__ Bt,
           void* __restrict__ Cv, const float* __restrict__ bias,
           int M, int N, int K, long sA, long sB, long sC, float scale)
{
  constexpr int U = (BN == 256) ? 4 : 3;
  constexpr int NREP = BN / 64;          // ni frags per wave (4 or 2)
  constexpr int NB = NREP / 2;           // frags per B half-set (2 or 1)
  __shared__ __align__(16) u16 As[2 * 256 * 64];       // 64 KiB
  __shared__ __align__(16) u16 Bs[2 * BN * 64];        // 64 / 32 KiB

  const int bz = blockIdx.z;
  const long m0 = (long)blockIdx.x * 256, n0 = (long)blockIdx.y * BN;
  const int tid = threadIdx.x;
  const int wave = tid >> 6, lane = tid & 63;
  const int wrg = wave >> 2, wcg = wave & 3;
  const int lg = lane >> 4, lr = lane & 15;

  const char* Ag = (const char*)(A + (long)bz * sA);
  const char* Bg = (const char*)(Bt + (long)bz * sB);
  const long ldA = (long)K * 2, ldB = (long)K * 2;
  const int NT = K >> 6;

  // fragment row/col bases (split so each phase's reads hit one 16KB unit)
  int amrow[8], bnrow[NREP];
  #pragma unroll
  for (int mi = 0; mi < 8; ++mi)
    amrow[mi] = (mi < 4) ? (wrg * 64 + mi * 16) : (128 + wrg * 64 + (mi - 4) * 16);
  #pragma unroll
  for (int ni = 0; ni < NREP; ++ni)
    bnrow[ni] = (BN == 256)
        ? ((ni < 2) ? (wcg * 32 + ni * 16) : (128 + wcg * 32 + (ni - 2) * 16))
        : (wcg * 32 + ni * 16);

  // stage one 16KB unit (128 rows x 64 k) with 2 global_load_lds calls;
  // global source pre-swizzled, LDS dest linear (wave-uniform base).
  auto stage16k = [&](const char* gRow0, long ld, u16* ldsUnit) {
    #pragma unroll
    for (int c = 0; c < 2; ++c) {
      const int idx = c * 8192 + wave * 1024 + lane * 16;
      const int r = idx >> 7;
      const int colb = (idx & 127) ^ ((r & 7) << 4);
      const char* src = gRow0 + (long)r * ld + colb;
      u16* dst = ldsUnit + ((c * 8192 + wave * 1024) >> 1);
      __builtin_amdgcn_global_load_lds(
          (const __attribute__((address_space(1))) void*)src,
          (__attribute__((address_space(3))) void*)dst, 16, 0, 0);
    }
  };

  auto issue = [&](int u) {
    if (u >= U * NT) return;
    const int tau = u / U, j = u % U, buf = tau & 1;
    const long kB = (long)tau * 128;
    if constexpr (U == 4) {
      if (j == 0)      stage16k(Ag + m0 * ldA + kB,         ldA, As + buf * 16384);
      else if (j == 1) stage16k(Bg + n0 * ldB + kB,         ldB, Bs + buf * (BN * 64));
      else if (j == 2) stage16k(Bg + (n0 + 128) * ldB + kB, ldB, Bs + buf * (BN * 64) + 8192);
      else             stage16k(Ag + (m0 + 128) * ldA + kB, ldA, As + buf * 16384 + 8192);
    } else {
      if (j == 0)      stage16k(Ag + m0 * ldA + kB,         ldA, As + buf * 16384);
      else if (j == 1) stage16k(Bg + n0 * ldB + kB,         ldB, Bs + buf * (BN * 64));
      else             stage16k(Ag + (m0 + 128) * ldA + kB, ldA, As + buf * 16384 + 8192);
    }
  };

  auto ldfrag = [&](const u16* bufBase, int row, int colb) -> bf16x8 {
    return *reinterpret_cast<const bf16x8*>(
        reinterpret_cast<const char*>(bufBase) + row * 128 + (colb ^ ((row & 7) << 4)));
  };

  f32x4 acc[8][NREP];
  #pragma unroll
  for (int i = 0; i < 8; ++i)
    #pragma unroll
    for (int j = 0; j < NREP; ++j)
      acc[i][j] = (f32x4){0.f, 0.f, 0.f, 0.f};

  bf16x8 a[4][2], b0[NB][2], b1[NB][2];

  // ---- prologue: issue 2U-1 units, land tile 0 ----
  int nextu = 0;
  for (; nextu < 2 * U - 1; ++nextu) issue(nextu);
  if constexpr (U == 4) asm volatile("s_waitcnt vmcnt(6)" ::: "memory");
  else                  asm volatile("s_waitcnt vmcnt(4)" ::: "memory");
  bar();

  for (int tt = 0; tt < NT; ++tt) {
    const int buf = tt & 1;
    const u16* Ab = As + buf * 16384;
    const u16* Bb = Bs + buf * (BN * 64);

    // ---- P1: read A-lo + B-set0; MFMA lo x set0 ----
    #pragma unroll
    for (int mi = 0; mi < 4; ++mi)
      #pragma unroll
      for (int ks = 0; ks < 2; ++ks)
        a[mi][ks] = ldfrag(Ab, amrow[mi] + lr, ks * 64 + lg * 16);
    #pragma unroll
    for (int nb = 0; nb < NB; ++nb)
      #pragma unroll
      for (int ks = 0; ks < 2; ++ks)
        b0[nb][ks] = ldfrag(Bb, bnrow[nb] + lr, ks * 64 + lg * 16);
    issue(nextu); ++nextu;
    bar();
    asm volatile("s_waitcnt lgkmcnt(0)" ::: "memory");
    __builtin_amdgcn_sched_barrier(0);
    __builtin_amdgcn_s_setprio(1);
    #pragma unroll
    for (int mi = 0; mi < 4; ++mi)
      #pragma unroll
      for (int nb = 0; nb < NB; ++nb)
        #pragma unroll
        for (int ks = 0; ks < 2; ++ks)
          acc[mi][nb] = __builtin_amdgcn_mfma_f32_16x16x32_bf16(a[mi][ks], b0[nb][ks], acc[mi][nb], 0, 0, 0);
    __builtin_amdgcn_s_setprio(0);
    bar();

    // ---- P2: read B-set1; MFMA lo x set1 ----
    #pragma unroll
    for (int nb = 0; nb < NB; ++nb)
      #pragma unroll
      for (int ks = 0; ks < 2; ++ks)
        b1[nb][ks] = ldfrag(Bb, bnrow[NB + nb] + lr, ks * 64 + lg * 16);
    issue(nextu); ++nextu;
    bar();
    asm volatile("s_waitcnt lgkmcnt(0)" ::: "memory");
    __builtin_amdgcn_sched_barrier(0);
    __builtin_amdgcn_s_setprio(1);
    #pragma unroll
    for (int mi = 0; mi < 4; ++mi)
      #pragma unroll
      for (int nb = 0; nb < NB; ++nb)
        #pragma unroll
        for (int ks = 0; ks < 2; ++ks)
          acc[mi][NB + nb] = __builtin_amdgcn_mfma_f32_16x16x32_bf16(a[mi][ks], b1[nb][ks], acc[mi][NB + nb], 0, 0, 0);
    __builtin_amdgcn_s_setprio(0);
    bar();

    // ---- P3: read A-hi (overwrite a); MFMA hi x set1 ----
    #pragma unroll
    for (int mi = 0; mi < 4; ++mi)
      #pragma unroll
      for (int ks = 0; ks < 2; ++ks)
        a[mi][ks] = ldfrag(Ab, amrow[4 + mi] + lr, ks * 64 + lg * 16);
    issue(nextu); ++nextu;
    bar();
    asm volatile("s_waitcnt lgkmcnt(0)" ::: "memory");
    __builtin_amdgcn_sched_barrier(0);
    __builtin_amdgcn_s_setprio(1);
    #pragma unroll
    for (int mi = 0; mi < 4; ++mi)
      #pragma unroll
      for (int nb = 0; nb < NB; ++nb)
        #pragma unroll
        for (int ks = 0; ks < 2; ++ks)
          acc[4 + mi][NB + nb] = __builtin_amdgcn_mfma_f32_16x16x32_bf16(a[mi][ks], b1[nb][ks], acc[4 + mi][NB + nb], 0, 0, 0);
    __builtin_amdgcn_s_setprio(0);
    bar();

    // ---- P4: no reads; MFMA hi x set0; tile-boundary counted vmcnt ----
    if constexpr (U == 4) { issue(nextu); ++nextu; }
    bar();
    __builtin_amdgcn_s_setprio(1);
    #pragma unroll
    for (int mi = 0; mi < 4; ++mi)
      #pragma unroll
      for (int nb = 0; nb < NB; ++nb)
        #pragma unroll
        for (int ks = 0; ks < 2; ++ks)
          acc[4 + mi][nb] = __builtin_amdgcn_mfma_f32_16x16x32_bf16(a[mi][ks], b0[nb][ks], acc[4 + mi][nb], 0, 0, 0);
    __builtin_amdgcn_s_setprio(0);
    if (tt + 1 < NT) {
      if (tt + 1 == NT - 1)      asm volatile("s_waitcnt vmcnt(0)" ::: "memory");
      else if constexpr (U == 4) asm volatile("s_waitcnt vmcnt(6)" ::: "memory");
      else                       asm volatile("s_waitcnt vmcnt(4)" ::: "memory");
      bar();
    }
  }

  // ---- epilogue ----
  #pragma unroll
  for (int mi = 0; mi < 8; ++mi) {
    #pragma unroll
    for (int ni = 0; ni < NREP; ++ni) {
      #pragma unroll
      for (int r = 0; r < 4; ++r) {
        const long grow = m0 + amrow[mi] + lg * 4 + r;
        const long gcol = n0 + bnrow[ni] + lr;
        const float v = acc[mi][ni][r];
        if constexpr (MODE == 0) {
          u16* Cp = (u16*)Cv + (long)bz * sC;
          Cp[grow * N + gcol] = f2bf(v);
        } else if constexpr (MODE == 1) {
          float* Cp = (float*)Cv + (long)bz * sC;
          Cp[grow * N + gcol] = v * scale;
        } else if constexpr (MODE == 2) {
          float* Cp = (float*)Cv + (long)bz * sC;
          Cp[grow * N + gcol] += v;
        } else if constexpr (MODE == 3) {
          u16* Cp = (u16*)Cv + (long)bz * sC;
          const float x = v + bias[gcol];
          const float ge = 0.5f * x * (1.0f + erff(x * 0.70710678118f));
          Cp[grow * N + gcol] = f2bf(ge);
        } else if constexpr (MODE == 4) {
          float* Cp = (float*)Cv + (long)bz * sC;
          const long idx = grow * N + gcol;
          Cp[idx] = Cp[idx] + v + bias[gcol];
        }
      }
    }
  }
}

// ---------------------------------------------------------------------------
// Per-layer weight transpose+convert: f32 [K][N] -> bf16 [N][K].
// ---------------------------------------------------------------------------
__global__ __launch_bounds__(256)
void trans_k(const float* __restrict__ wq, const float* __restrict__ wk,
             const float* __restrict__ wv, const float* __restrict__ w1,
             const float* __restrict__ w2, u16* __restrict__ ob)
{
  __shared__ u16 T[64][68];
  const int b = blockIdx.x;
  const float* in; u16* out; int K, N, tk, tn;
  if (b < 768) {
    const int m = b >> 8, tt = b & 255;
    in = (m == 0) ? wq : (m == 1) ? wk : wv;
    out = ob + (long)m * 1048576L;
    K = 1024; N = 1024; tk = tt >> 4; tn = tt & 15;
  } else if (b < 1792) {
    const int tt = b - 768;
    in = w1; out = ob + 3L * 1048576L; K = 1024; N = 4096;
    tk = tt >> 6; tn = tt & 63;
  } else {
    const int tt = b - 1792;
    in = w2; out = ob + 7L * 1048576L; K = 4096; N = 1024;
    tk = tt >> 4; tn = tt & 15;
  }
  const int k0 = tk * 64, n0 = tn * 64;
  const int t = threadIdx.x;
  {
    const int r = t >> 2, cq = (t & 3) * 16;
    const float* src = in + (long)(k0 + r) * N + n0 + cq;
    #pragma unroll
    for (int q = 0; q < 4; ++q) {
      const float4 v = *reinterpret_cast<const float4*>(src + q * 4);
      T[r][cq + q * 4 + 0] = f2bf(v.x);
      T[r][cq + q * 4 + 1] = f2bf(v.y);
      T[r][cq + q * 4 + 2] = f2bf(v.z);
      T[r][cq + q * 4 + 3] = f2bf(v.w);
    }
  }
  __syncthreads();
  {
    const int n = t >> 2, kq2 = (t & 3) * 16;
    u16 tmp[16];
    #pragma unroll
    for (int j = 0; j < 16; ++j) tmp[j] = T[kq2 + j][n];
    uint4* dst = reinterpret_cast<uint4*>(out + (long)(n0 + n) * K + k0 + kq2);
    dst[0] = *reinterpret_cast<const uint4*>(&tmp[0]);
    dst[1] = *reinterpret_cast<const uint4*>(&tmp[8]);
  }
}

// ---------------------------------------------------------------------------
__global__ __launch_bounds__(256)
void embed_k(const int* __restrict__ xt, const int* __restrict__ zi,
             const float* __restrict__ pos, const float* __restrict__ temb,
             float* __restrict__ H)
{
  const int bt = blockIdx.x;
  const int b = bt >> 10, tk = bt & 1023;
  const int d = threadIdx.x * 4;
  const float4 p = reinterpret_cast<const float4*>(pos + (long)tk * 1024)[threadIdx.x];
  float4 v;
  if (tk < 512) {
    const float z = (float)zi[b * 512 + tk];
    const float c0 = (float)(d + 0) - z, c1 = (float)(d + 1) - z;
    const float c2 = (float)(d + 2) - z, c3 = (float)(d + 3) - z;
    v.x = (d + 0 < 10) ? -0.5f * c0 * c0 : 0.f;
    v.y = (d + 1 < 10) ? -0.5f * c1 * c1 : 0.f;
    v.z = (d + 2 < 10) ? -0.5f * c2 * c2 : 0.f;
    v.w = (d + 3 < 10) ? -0.5f * c3 * c3 : 0.f;
  } else {
    const float* te = temb + (long)xt[b * 512 + (tk - 512)] * 1024;
    v = reinterpret_cast<const float4*>(te)[threadIdx.x];
  }
  float4 o; o.x = v.x + p.x; o.y = v.y + p.y; o.z = v.z + p.z; o.w = v.w + p.w;
  reinterpret_cast<float4*>(H + (long)bt * 1024)[threadIdx.x] = o;
}

__global__ __launch_bounds__(256)
void ln_k(const float* __restrict__ X, const float* __restrict__ g,
          const float* __restrict__ bta, u16* __restrict__ Y)
{
  __shared__ float sm[8];
  const long row = blockIdx.x;
  const float4 x = reinterpret_cast<const float4*>(X + row * 1024)[threadIdx.x];
  float s1 = x.x + x.y + x.z + x.w;
  float s2 = x.x * x.x + x.y * x.y + x.z * x.z + x.w * x.w;
  #pragma unroll
  for (int o = 32; o > 0; o >>= 1) { s1 += __shfl_down(s1, o); s2 += __shfl_down(s2, o); }
  const int w = threadIdx.x >> 6, ln = threadIdx.x & 63;
  if (ln == 0) { sm[w] = s1; sm[4 + w] = s2; }
  __syncthreads();
  s1 = sm[0] + sm[1] + sm[2] + sm[3];
  s2 = sm[4] + sm[5] + sm[6] + sm[7];
  const float mu = s1 * (1.f / 1024.f);
  const float var = s2 * (1.f / 1024.f) - mu * mu;
  const float inv = rsqrtf(var + 1e-5f);
  const float4 gg = reinterpret_cast<const float4*>(g)[threadIdx.x];
  const float4 bb = reinterpret_cast<const float4*>(bta)[threadIdx.x];
  const u32 o0 = (u32)f2bf((x.x - mu) * inv * gg.x + bb.x) | ((u32)f2bf((x.y - mu) * inv * gg.y + bb.y) << 16);
  const u32 o1 = (u32)f2bf((x.z - mu) * inv * gg.z + bb.z) | ((u32)f2bf((x.w - mu) * inv * gg.w + bb.w) << 16);
  reinterpret_cast<uint2*>(Y + row * 1024)[threadIdx.x] = make_uint2(o0, o1);
}

__global__ __launch_bounds__(256)
void sm_k(const float* __restrict__ S, u16* __restrict__ P)
{
  __shared__ float sm[8];
  const long row = blockIdx.x;
  const float4 x = reinterpret_cast<const float4*>(S + row * 1024)[threadIdx.x];
  float m = fmaxf(fmaxf(x.x, x.y), fmaxf(x.z, x.w));
  #pragma unroll
  for (int o = 32; o > 0; o >>= 1) m = fmaxf(m, __shfl_down(m, o));
  const int w = threadIdx.x >> 6, ln = threadIdx.x & 63;
  if (ln == 0) sm[w] = m;
  __syncthreads();
  m = fmaxf(fmaxf(sm[0], sm[1]), fmaxf(sm[2], sm[3]));
  const float e0 = __expf(x.x - m), e1 = __expf(x.y - m);
  const float e2 = __expf(x.z - m), e3 = __expf(x.w - m);
  float s = e0 + e1 + e2 + e3;
  #pragma unroll
  for (int o = 32; o > 0; o >>= 1) s += __shfl_down(s, o);
  if (ln == 0) sm[4 + w] = s;
  __syncthreads();
  const float tot = sm[4] + sm[5] + sm[6] + sm[7];
  const float r = 1.0f / tot;
  const u32 o0 = (u32)f2bf(e0 * r) | ((u32)f2bf(e1 * r) << 16);
  const u32 o1 = (u32)f2bf(e2 * r) | ((u32)f2bf(e3 * r) << 16);
  reinterpret_cast<uint2*>(P + row * 1024)[threadIdx.x] = make_uint2(o0, o1);
}

__global__ __launch_bounds__(256)
void ro_k(const float* __restrict__ H, const float* __restrict__ w,
          const float* __restrict__ b, float* __restrict__ out)
{
  __shared__ float sm[4];
  const int row = blockIdx.x;
  const int bb = row >> 9, i = row & 511;
  const float* h = H + ((long)bb * 1024 + i) * 1024;
  const float4 x = reinterpret_cast<const float4*>(h)[threadIdx.x];
  const float4 ww = reinterpret_cast<const float4*>(w)[threadIdx.x];
  float s = x.x * ww.x + x.y * ww.y + x.z * ww.z + x.w * ww.w;
  #pragma unroll
  for (int o = 32; o > 0; o >>= 1) s += __shfl_down(s, o);
  const int wv = threadIdx.x >> 6, ln = threadIdx.x & 63;
  if (ln == 0) sm[wv] = s;
  __syncthreads();
  if (threadIdx.x == 0) out[row] = sm[0] + sm[1] + sm[2] + sm[3] + b[0];
}

// ---------------------------------------------------------------------------
extern "C" void kernel_launch(void* const* d_in, const int* in_sizes, int n_in,
                              void* d_out, int out_size, void* d_ws, size_t ws_size,
                              hipStream_t stream)
{
  const int* xt = (const int*)d_in[0];
  const int* zi = (const int*)d_in[1];
  const float* pos  = (const float*)d_in[2];
  const float* temb = (const float*)d_in[3];
  const float* Wq = (const float*)d_in[4];
  const float* Wk = (const float*)d_in[5];
  const float* Wv = (const float*)d_in[6];
  const float* ln1g = (const float*)d_in[7];
  const float* ln1b = (const float*)d_in[8];
  const float* ln2g = (const float*)d_in[9];
  const float* ln2b = (const float*)d_in[10];
  const float* w1 = (const float*)d_in[11];
  const float* b1 = (const float*)d_in[12];
  const float* w2 = (const float*)d_in[13];
  const float* b2 = (const float*)d_in[14];
  const float* row_w = (const float*)d_in[15];
  const float* row_b = (const float*)d_in[16];

  char* ws = (char*)d_ws;
  const long MB = 1024 * 1024;
  float* H   = (float*)(ws + 0);          // 32 MB  [8][1024][1024] f32
  u16*   H1  = (u16*)(ws + 32 * MB);      // 16 MB  [8192][1024] bf16
  u16*   Qb  = (u16*)(ws + 48 * MB);      // 16 MB
  u16*   Kb  = (u16*)(ws + 64 * MB);      // 16 MB
  u16*   Vt  = (u16*)(ws + 80 * MB);      // 16 MB  [8][1024(d)][1024(t)]
  float* S   = (float*)(ws + 96 * MB);    // 32 MB  f32
  u16*   P   = (u16*)(ws + 128 * MB);     // 16 MB
  u16*   G   = (u16*)(ws + 80 * MB);      // 64 MB, aliases Vt/S/P (dead in MLP)
  u16*   WT  = (u16*)(ws + 144 * MB);     // 22 MB  per-layer bf16 weights (B^T)

  u16* WqT = WT;
  u16* WkT = WT + 1048576L;
  u16* WvT = WT + 2 * 1048576L;
  u16* W1T = WT + 3 * 1048576L;           // [4096][1024]
  u16* W2T = WT + 7 * 1048576L;           // [1024][4096]

  const long s1M = 1024L * 1024L;

  embed_k<<<8192, 256, 0, stream>>>(xt, zi, pos, temb, H);

  for (int l = 0; l < 12; ++l) {
    const float* wq = Wq + (long)l * s1M;
    const float* wk = Wk + (long)l * s1M;
    const float* wv = Wv + (long)l * s1M;
    const float* mw1 = w1 + (long)l * 1024L * 4096L;
    const float* mb1 = b1 + (long)l * 4096L;
    const float* mw2 = w2 + (long)l * 4096L * 1024L;
    const float* mb2 = b2 + (long)l * 1024L;

    trans_k<<<2816, 256, 0, stream>>>(wq, wk, wv, mw1, mw2, WT);

    ln_k<<<8192, 256, 0, stream>>>(H, ln1g + l * 1024, ln1b + l * 1024, H1);

    // Q = H1 @ wq, K = H1 @ wk
    gemm8<0,128><<<dim3(32, 8, 1), 512, 0, stream>>>(H1, WqT, Qb, nullptr, 8192, 1024, 1024, 0, 0, 0, 1.f);
    gemm8<0,128><<<dim3(32, 8, 1), 512, 0, stream>>>(H1, WkT, Kb, nullptr, 8192, 1024, 1024, 0, 0, 0, 1.f);
    // Vt[b][d][t] = sum_k WvT[d][k] H1[b][t][k]
    gemm8<0,128><<<dim3(4, 8, 8), 512, 0, stream>>>(WvT, H1, Vt, nullptr, 1024, 1024, 1024, 0, s1M, s1M, 1.f);

    // S = Q @ K^T / sqrt(D)
    gemm8<1,128><<<dim3(4, 8, 8), 512, 0, stream>>>(Qb, Kb, S, nullptr, 1024, 1024, 1024, s1M, s1M, s1M, 1.f / 32.f);

    sm_k<<<8192, 256, 0, stream>>>(S, P);

    // H += P @ V
    gemm8<2,128><<<dim3(4, 8, 8), 512, 0, stream>>>(P, Vt, (void*)H, nullptr, 1024, 1024, 1024, s1M, s1M, s1M, 1.f);

    ln_k<<<8192, 256, 0, stream>>>(H, ln2g + l * 1024, ln2b + l * 1024, H1);

    // G = gelu(H1 @ w1 + b1)
    gemm8<3,256><<<dim3(32, 16, 1), 512, 0, stream>>>(H1, W1T, G, mb1, 8192, 4096, 1024, 0, 0, 0, 1.f);
    // H += G @ w2 + b2
    gemm8<4,128><<<dim3(32, 8, 1), 512, 0, stream>>>(G, W2T, (void*)H, mb2, 8192, 1024, 4096, 0, 0, 0, 1.f);
  }

  ro_k<<<4096, 256, 0, stream>>>(H, row_w, row_b, (float*)d_out);
}

// Round 4
// 4290.175 us; speedup vs baseline: 1.5681x; 1.1502x over previous
//
#include <hip/hip_runtime.h>
#include <cstdint>
#include <cmath>

typedef unsigned short u16;
typedef unsigned int u32;
typedef short bf16x8 __attribute__((ext_vector_type(8)));
typedef float f32x4 __attribute__((ext_vector_type(4)));

#define DEV static __device__ __forceinline__

DEV u16 f2bf(float f) {
  union { float f; u32 u; } v; v.f = f;
  return (u16)((v.u + 0x7FFFu + ((v.u >> 16) & 1u)) >> 16);
}
DEV float bf2f(u32 lo16) {
  union { u32 u; float f; } v; v.u = lo16 << 16; return v.f;
}

DEV void gload16(const void* g, u16* l) {
  __builtin_amdgcn_global_load_lds(
      (const __attribute__((address_space(1))) void*)g,
      (__attribute__((address_space(3))) void*)l, 16, 0, 0);
}

// ---------------------------------------------------------------------------
// 128x128 bf16 GEMM, BK=64, 4 waves, 2-phase (high-occupancy), T2-swizzled
// LDS. A [M][ldA] bf16, Bt [N][ldB] bf16 (B transposed). global_load_lds
// width-16 staging with pre-swizzled global source (swizzle byte^=(row&7)<<4,
// both-sides involution, rule #21); fragment ds_read_b128 conflict-free
// (verified 0 conflicts in r3). 32 MFMA per barrier pair (2x r2 density).
// ~3 blocks/CU -> cross-block wave overlap hides barrier drains (m114).
// MODE 0: out bf16 = v*scale | 2: f32 += | 3: bf16 gelu(v+bias) |
// MODE 4: f32 += v + bias
// ---------------------------------------------------------------------------
template<int MODE>
__global__ __launch_bounds__(256)
void gemmA(const u16* __restrict__ A, const u16* __restrict__ Bt,
           void* __restrict__ Cv, const float* __restrict__ bias,
           int M, int N, int K, int ldA, int ldB,
           long sA, long sB, long sC, float scale)
{
  __shared__ __align__(16) u16 As[128 * 64];   // 16 KiB
  __shared__ __align__(16) u16 Bs[128 * 64];   // 16 KiB

  const int bz = blockIdx.z;
  const long m0 = (long)blockIdx.x * 128, n0 = (long)blockIdx.y * 128;
  const int t = threadIdx.x;
  const int wave = t >> 6, lane = t & 63;
  const int wr = (wave >> 1) * 64, wc = (wave & 1) * 64;
  const int lg = lane >> 4, lr = lane & 15;

  const long ldA2 = (long)ldA * 2, ldB2 = (long)ldB * 2;

  // staging: 16 chunks of 1KB per operand tile (128 rows x 128B). chunk
  // q = c*4+wave covers rows q*8..q*8+7. lane -> row q*8+(lane>>3),
  // byte (lane&7)*16, global source pre-swizzled by ^(rowlocal<<4).
  const int rl = lane >> 3, c7 = lane & 7;
  const int sb = (c7 * 16) ^ (rl << 4);
  const char* aP[4]; const char* bP[4];
  u16* aL[4]; u16* bL[4];
  {
    const char* Ab = (const char*)(A + (long)bz * sA);
    const char* Bb = (const char*)(Bt + (long)bz * sB);
    #pragma unroll
    for (int c = 0; c < 4; ++c) {
      const int q = c * 4 + wave;
      aP[c] = Ab + (m0 + q * 8 + rl) * ldA2 + sb;
      bP[c] = Bb + (n0 + q * 8 + rl) * ldB2 + sb;
      aL[c] = As + q * 512;
      bL[c] = Bs + q * 512;
    }
  }

  // fragment reads: row & 7 == lr & 7 for every fragment row -> constant swz
  const int rswz = (lr & 7) << 4;
  auto rd = [&](const u16* base, int row, int cbyte) -> bf16x8 {
    return *reinterpret_cast<const bf16x8*>(
        reinterpret_cast<const char*>(base) + row * 128 + (cbyte ^ rswz));
  };

  f32x4 acc[4][4];
  #pragma unroll
  for (int i = 0; i < 4; ++i)
    #pragma unroll
    for (int j = 0; j < 4; ++j)
      acc[i][j] = (f32x4){0.f, 0.f, 0.f, 0.f};

  for (int k0 = 0; k0 < K; k0 += 64) {
    #pragma unroll
    for (int c = 0; c < 4; ++c) {
      gload16(aP[c], aL[c]);
      gload16(bP[c], bL[c]);
      aP[c] += 128; bP[c] += 128;
    }
    __syncthreads();   // drains vmcnt -> staged data visible

    #pragma unroll
    for (int ks = 0; ks < 2; ++ks) {
      bf16x8 a[4], b[4];
      #pragma unroll
      for (int i = 0; i < 4; ++i)
        a[i] = rd(As, wr + i * 16 + lr, ks * 64 + lg * 16);
      #pragma unroll
      for (int i = 0; i < 4; ++i)
        b[i] = rd(Bs, wc + i * 16 + lr, ks * 64 + lg * 16);
      #pragma unroll
      for (int mi = 0; mi < 4; ++mi)
        #pragma unroll
        for (int ni = 0; ni < 4; ++ni)
          acc[mi][ni] = __builtin_amdgcn_mfma_f32_16x16x32_bf16(a[mi], b[ni], acc[mi][ni], 0, 0, 0);
    }
    __syncthreads();   // reads drained before next overwrite
  }

  #pragma unroll
  for (int mi = 0; mi < 4; ++mi) {
    #pragma unroll
    for (int ni = 0; ni < 4; ++ni) {
      #pragma unroll
      for (int r = 0; r < 4; ++r) {
        const long grow = m0 + wr + mi * 16 + lg * 4 + r;
        const long gcol = n0 + wc + ni * 16 + lr;
        const float v = acc[mi][ni][r];
        if constexpr (MODE == 0) {
          u16* Cp = (u16*)Cv + (long)bz * sC;
          Cp[grow * N + gcol] = f2bf(v * scale);
        } else if constexpr (MODE == 2) {
          float* Cp = (float*)Cv + (long)bz * sC;
          Cp[grow * N + gcol] += v;
        } else if constexpr (MODE == 3) {
          u16* Cp = (u16*)Cv + (long)bz * sC;
          const float x = v + bias[gcol];
          const float ge = 0.5f * x * (1.0f + erff(x * 0.70710678118f));
          Cp[grow * N + gcol] = f2bf(ge);
        } else if constexpr (MODE == 4) {
          float* Cp = (float*)Cv + (long)bz * sC;
          const long idx = grow * N + gcol;
          Cp[idx] = Cp[idx] + v + bias[gcol];
        }
      }
    }
  }
}

// ---------------------------------------------------------------------------
// Per-layer weight transpose+convert: f32 [K][N] -> bf16 [N][K].
// Outputs: WqT+0, WkT+1M (contiguous => QK concat weight [2048][1024]),
// WvT+2M, W1T+3M, W2T+7M (u16 elements).
// ---------------------------------------------------------------------------
__global__ __launch_bounds__(256)
void trans_k(const float* __restrict__ wq, const float* __restrict__ wk,
             const float* __restrict__ wv, const float* __restrict__ w1,
             const float* __restrict__ w2, u16* __restrict__ ob)
{
  __shared__ u16 T[64][68];
  const int b = blockIdx.x;
  const float* in; u16* out; int K, N, tk, tn;
  if (b < 768) {
    const int m = b >> 8, tt = b & 255;
    in = (m == 0) ? wq : (m == 1) ? wk : wv;
    out = ob + (long)m * 1048576L;
    K = 1024; N = 1024; tk = tt >> 4; tn = tt & 15;
  } else if (b < 1792) {
    const int tt = b - 768;
    in = w1; out = ob + 3L * 1048576L; K = 1024; N = 4096;
    tk = tt >> 6; tn = tt & 63;
  } else {
    const int tt = b - 1792;
    in = w2; out = ob + 7L * 1048576L; K = 4096; N = 1024;
    tk = tt >> 4; tn = tt & 15;
  }
  const int k0 = tk * 64, n0 = tn * 64;
  const int t = threadIdx.x;
  {
    const int r = t >> 2, cq = (t & 3) * 16;
    const float* src = in + (long)(k0 + r) * N + n0 + cq;
    #pragma unroll
    for (int q = 0; q < 4; ++q) {
      const float4 v = *reinterpret_cast<const float4*>(src + q * 4);
      T[r][cq + q * 4 + 0] = f2bf(v.x);
      T[r][cq + q * 4 + 1] = f2bf(v.y);
      T[r][cq + q * 4 + 2] = f2bf(v.z);
      T[r][cq + q * 4 + 3] = f2bf(v.w);
    }
  }
  __syncthreads();
  {
    const int n = t >> 2, kq2 = (t & 3) * 16;
    u16 tmp[16];
    #pragma unroll
    for (int j = 0; j < 16; ++j) tmp[j] = T[kq2 + j][n];
    uint4* dst = reinterpret_cast<uint4*>(out + (long)(n0 + n) * K + k0 + kq2);
    dst[0] = *reinterpret_cast<const uint4*>(&tmp[0]);
    dst[1] = *reinterpret_cast<const uint4*>(&tmp[8]);
  }
}

// ---------------------------------------------------------------------------
__global__ __launch_bounds__(256)
void embed_k(const int* __restrict__ xt, const int* __restrict__ zi,
             const float* __restrict__ pos, const float* __restrict__ temb,
             float* __restrict__ H)
{
  const int bt = blockIdx.x;
  const int b = bt >> 10, tk = bt & 1023;
  const int d = threadIdx.x * 4;
  const float4 p = reinterpret_cast<const float4*>(pos + (long)tk * 1024)[threadIdx.x];
  float4 v;
  if (tk < 512) {
    const float z = (float)zi[b * 512 + tk];
    const float c0 = (float)(d + 0) - z, c1 = (float)(d + 1) - z;
    const float c2 = (float)(d + 2) - z, c3 = (float)(d + 3) - z;
    v.x = (d + 0 < 10) ? -0.5f * c0 * c0 : 0.f;
    v.y = (d + 1 < 10) ? -0.5f * c1 * c1 : 0.f;
    v.z = (d + 2 < 10) ? -0.5f * c2 * c2 : 0.f;
    v.w = (d + 3 < 10) ? -0.5f * c3 * c3 : 0.f;
  } else {
    const float* te = temb + (long)xt[b * 512 + (tk - 512)] * 1024;
    v = reinterpret_cast<const float4*>(te)[threadIdx.x];
  }
  float4 o; o.x = v.x + p.x; o.y = v.y + p.y; o.z = v.z + p.z; o.w = v.w + p.w;
  reinterpret_cast<float4*>(H + (long)bt * 1024)[threadIdx.x] = o;
}

__global__ __launch_bounds__(256)
void ln_k(const float* __restrict__ X, const float* __restrict__ g,
          const float* __restrict__ bta, u16* __restrict__ Y)
{
  __shared__ float sm[8];
  const long row = blockIdx.x;
  const float4 x = reinterpret_cast<const float4*>(X + row * 1024)[threadIdx.x];
  float s1 = x.x + x.y + x.z + x.w;
  float s2 = x.x * x.x + x.y * x.y + x.z * x.z + x.w * x.w;
  #pragma unroll
  for (int o = 32; o > 0; o >>= 1) { s1 += __shfl_down(s1, o); s2 += __shfl_down(s2, o); }
  const int w = threadIdx.x >> 6, ln = threadIdx.x & 63;
  if (ln == 0) { sm[w] = s1; sm[4 + w] = s2; }
  __syncthreads();
  s1 = sm[0] + sm[1] + sm[2] + sm[3];
  s2 = sm[4] + sm[5] + sm[6] + sm[7];
  const float mu = s1 * (1.f / 1024.f);
  const float var = s2 * (1.f / 1024.f) - mu * mu;
  const float inv = rsqrtf(var + 1e-5f);
  const float4 gg = reinterpret_cast<const float4*>(g)[threadIdx.x];
  const float4 bb = reinterpret_cast<const float4*>(bta)[threadIdx.x];
  const u32 o0 = (u32)f2bf((x.x - mu) * inv * gg.x + bb.x) | ((u32)f2bf((x.y - mu) * inv * gg.y + bb.y) << 16);
  const u32 o1 = (u32)f2bf((x.z - mu) * inv * gg.z + bb.z) | ((u32)f2bf((x.w - mu) * inv * gg.w + bb.w) << 16);
  reinterpret_cast<uint2*>(Y + row * 1024)[threadIdx.x] = make_uint2(o0, o1);
}

// Row softmax over 1024 cols, bf16 in -> bf16 out
__global__ __launch_bounds__(256)
void sm_k(const u16* __restrict__ S, u16* __restrict__ P)
{
  __shared__ float sm[8];
  const long row = blockIdx.x;
  const uint2 raw = reinterpret_cast<const uint2*>(S + row * 1024)[threadIdx.x];
  const float x0 = bf2f(raw.x & 0xffffu), x1 = bf2f(raw.x >> 16);
  const float x2 = bf2f(raw.y & 0xffffu), x3 = bf2f(raw.y >> 16);
  float m = fmaxf(fmaxf(x0, x1), fmaxf(x2, x3));
  #pragma unroll
  for (int o = 32; o > 0; o >>= 1) m = fmaxf(m, __shfl_down(m, o));
  const int w = threadIdx.x >> 6, ln = threadIdx.x & 63;
  if (ln == 0) sm[w] = m;
  __syncthreads();
  m = fmaxf(fmaxf(sm[0], sm[1]), fmaxf(sm[2], sm[3]));
  const float e0 = __expf(x0 - m), e1 = __expf(x1 - m);
  const float e2 = __expf(x2 - m), e3 = __expf(x3 - m);
  float s = e0 + e1 + e2 + e3;
  #pragma unroll
  for (int o = 32; o > 0; o >>= 1) s += __shfl_down(s, o);
  if (ln == 0) sm[4 + w] = s;
  __syncthreads();
  const float tot = sm[4] + sm[5] + sm[6] + sm[7];
  const float r = 1.0f / tot;
  const u32 o0 = (u32)f2bf(e0 * r) | ((u32)f2bf(e1 * r) << 16);
  const u32 o1 = (u32)f2bf(e2 * r) | ((u32)f2bf(e3 * r) << 16);
  reinterpret_cast<uint2*>(P + row * 1024)[threadIdx.x] = make_uint2(o0, o1);
}

__global__ __launch_bounds__(256)
void ro_k(const float* __restrict__ H, const float* __restrict__ w,
          const float* __restrict__ b, float* __restrict__ out)
{
  __shared__ float sm[4];
  const int row = blockIdx.x;
  const int bb = row >> 9, i = row & 511;
  const float* h = H + ((long)bb * 1024 + i) * 1024;
  const float4 x = reinterpret_cast<const float4*>(h)[threadIdx.x];
  const float4 ww = reinterpret_cast<const float4*>(w)[threadIdx.x];
  float s = x.x * ww.x + x.y * ww.y + x.z * ww.z + x.w * ww.w;
  #pragma unroll
  for (int o = 32; o > 0; o >>= 1) s += __shfl_down(s, o);
  const int wv = threadIdx.x >> 6, ln = threadIdx.x & 63;
  if (ln == 0) sm[wv] = s;
  __syncthreads();
  if (threadIdx.x == 0) out[row] = sm[0] + sm[1] + sm[2] + sm[3] + b[0];
}

// ---------------------------------------------------------------------------
extern "C" void kernel_launch(void* const* d_in, const int* in_sizes, int n_in,
                              void* d_out, int out_size, void* d_ws, size_t ws_size,
                              hipStream_t stream)
{
  const int* xt = (const int*)d_in[0];
  const int* zi = (const int*)d_in[1];
  const float* pos  = (const float*)d_in[2];
  const float* temb = (const float*)d_in[3];
  const float* Wq = (const float*)d_in[4];
  const float* Wk = (const float*)d_in[5];
  const float* Wv = (const float*)d_in[6];
  const float* ln1g = (const float*)d_in[7];
  const float* ln1b = (const float*)d_in[8];
  const float* ln2g = (const float*)d_in[9];
  const float* ln2b = (const float*)d_in[10];
  const float* w1 = (const float*)d_in[11];
  const float* b1 = (const float*)d_in[12];
  const float* w2 = (const float*)d_in[13];
  const float* b2 = (const float*)d_in[14];
  const float* row_w = (const float*)d_in[15];
  const float* row_b = (const float*)d_in[16];

  char* ws = (char*)d_ws;
  const long MB = 1024 * 1024;
  float* H   = (float*)(ws + 0);          // 32 MB  [8][1024][1024] f32
  u16*   H1  = (u16*)(ws + 32 * MB);      // 16 MB  [8192][1024] bf16
  u16*   QK  = (u16*)(ws + 48 * MB);      // 32 MB  [8192][2048] bf16 (Q||K)
  u16*   Vt  = (u16*)(ws + 80 * MB);      // 16 MB  [8][1024(d)][1024(t)]
  u16*   S   = (u16*)(ws + 96 * MB);      // 16 MB  bf16
  u16*   P   = (u16*)(ws + 112 * MB);     // 16 MB
  u16*   G   = (u16*)(ws + 80 * MB);      // 64 MB, aliases Vt/S/P (dead in MLP)
  u16*   WT  = (u16*)(ws + 144 * MB);     // 22 MB  per-layer bf16 weights (B^T)

  u16* WvT = WT + 2 * 1048576L;
  u16* W1T = WT + 3 * 1048576L;           // [4096][1024]
  u16* W2T = WT + 7 * 1048576L;           // [1024][4096]

  const long s1M = 1024L * 1024L;
  const long s2M = 2L * 1024L * 1024L;

  embed_k<<<8192, 256, 0, stream>>>(xt, zi, pos, temb, H);

  for (int l = 0; l < 12; ++l) {
    const float* wq = Wq + (long)l * s1M;
    const float* wk = Wk + (long)l * s1M;
    const float* wv = Wv + (long)l * s1M;
    const float* mw1 = w1 + (long)l * 1024L * 4096L;
    const float* mb1 = b1 + (long)l * 4096L;
    const float* mw2 = w2 + (long)l * 4096L * 1024L;
    const float* mb2 = b2 + (long)l * 1024L;

    trans_k<<<2816, 256, 0, stream>>>(wq, wk, wv, mw1, mw2, WT);

    ln_k<<<8192, 256, 0, stream>>>(H, ln1g + l * 1024, ln1b + l * 1024, H1);

    // [Q||K] = H1 @ [wq||wk]  (M=8192, N=2048, WqT/WkT contiguous at WT)
    gemmA<0><<<dim3(64, 16, 1), 256, 0, stream>>>(H1, WT, QK, nullptr,
        8192, 2048, 1024, 1024, 1024, 0, 0, 0, 1.f);
    // Vt[b][d][t] = sum_k WvT[d][k] H1[b][t][k]
    gemmA<0><<<dim3(8, 8, 8), 256, 0, stream>>>(WvT, H1, Vt, nullptr,
        1024, 1024, 1024, 1024, 1024, 0, s1M, s1M, 1.f);

    // S = Q @ K^T / 32  (A = QK cols 0..1023 ld 2048, Bt = QK cols 1024.. )
    gemmA<0><<<dim3(8, 8, 8), 256, 0, stream>>>(QK, QK + 1024, S, nullptr,
        1024, 1024, 1024, 2048, 2048, s2M, s2M, s1M, 1.f / 32.f);

    sm_k<<<8192, 256, 0, stream>>>(S, P);

    // H += P @ V
    gemmA<2><<<dim3(8, 8, 8), 256, 0, stream>>>(P, Vt, (void*)H, nullptr,
        1024, 1024, 1024, 1024, 1024, s1M, s1M, s1M, 1.f);

    ln_k<<<8192, 256, 0, stream>>>(H, ln2g + l * 1024, ln2b + l * 1024, H1);

    // G = gelu(H1 @ w1 + b1)
    gemmA<3><<<dim3(64, 32, 1), 256, 0, stream>>>(H1, W1T, G, mb1,
        8192, 4096, 1024, 1024, 1024, 0, 0, 0, 1.f);
    // H += G @ w2 + b2
    gemmA<4><<<dim3(64, 8, 1), 256, 0, stream>>>(G, W2T, (void*)H, mb2,
        8192, 1024, 4096, 4096, 4096, 0, 0, 0, 1.f);
  }

  ro_k<<<4096, 256, 0, stream>>>(H, row_w, row_b, (float*)d_out);
}